// Round 3
// baseline (133.122 us; speedup 1.0000x reference)
//
#include <hip/hip_runtime.h>

// Regime-switching KF — quad-decomposed + PACKED PAIRS: 4 lanes per series
// PAIR. Lanes 0..2 of each aligned quad own factor row j for TWO series
// (series A in .x, series B in .y of v2f); all arithmetic is <2 x float> so
// the compiler emits full-rate packed fp32 (v_pk_fma_f32 etc.) — one
// instruction covers both series at the same DAG depth. DPP cross-lane moves
// are 32-bit, applied per half. 32768 threads = 512 waves (1 wave on half
// the SIMDs) — wins because the machine was latency-bound at 1 wave/SIMD
// (VALUBusy 51%): per-wave serial time is ~unchanged while covering 2x
// series per wave.
// Lane 3 of each quad has all its multiplicative constants zero-masked so
// every quad-sum contribution from it is exactly 0.0f -> no z3 cndmasks.
// (verified by hand: lane-3 state stays exactly 0; det=1; quad_perm lane 3
// reads itself for ROTL/ROTR so no junk feeds back; no NaN paths)
// 3x3 inversion in row form unchanged: cof_row_j = M_row_{j+1} x M_row_{j+2},
// det = M_row_j . cof_row_j, Ci_row_j = (S*cof)_row_j / det.
// R2 note: resubmission — two prior "container failed twice" errors diagnosed
// as infra (bounds + lane algebra + codegen hazards all audited clean).

typedef float v2f __attribute__((ext_vector_type(2)));

static __device__ __forceinline__ float frcp(float x)  { return __builtin_amdgcn_rcpf(x); }
static __device__ __forceinline__ float frsq(float x)  { return __builtin_amdgcn_rsqf(x); }
static __device__ __forceinline__ float fexp2(float x) { return __builtin_amdgcn_exp2f(x); }
static __device__ __forceinline__ float flog2(float x) { return __builtin_amdgcn_logf(x); }

template <int CTRL>
static __device__ __forceinline__ float dppf(float x) {
    int i = __float_as_int(x);
    i = __builtin_amdgcn_mov_dpp(i, CTRL, 0xF, 0xF, true);
    return __int_as_float(i);
}
#define ROTL 0xC9   // quad_perm [1,2,0,3]: lane j reads lane j+1 (mod 3)
#define ROTR 0xD2   // quad_perm [2,0,1,3]: lane j reads lane j+2
#define XOR1 0xB1   // quad_perm [1,0,3,2]
#define XOR2 0x4E   // quad_perm [2,3,0,1]

template <int CTRL>
static __device__ __forceinline__ v2f dpp2(v2f v) {
    v2f r; r.x = dppf<CTRL>(v.x); r.y = dppf<CTRL>(v.y); return r;
}
static __device__ __forceinline__ v2f qsum2(v2f x) {   // sum over the quad, both halves
    x += dpp2<XOR1>(x);
    x += dpp2<XOR2>(x);
    return x;
}
static __device__ __forceinline__ v2f sp(float x) { return (v2f){x, x}; }
static __device__ __forceinline__ v2f rcp2(v2f a)  { return (v2f){frcp(a.x),  frcp(a.y)};  }
static __device__ __forceinline__ v2f rsq2(v2f a)  { return (v2f){frsq(a.x),  frsq(a.y)};  }
static __device__ __forceinline__ v2f exp22(v2f a) { return (v2f){fexp2(a.x), fexp2(a.y)}; }
static __device__ __forceinline__ v2f log22(v2f a) { return (v2f){flog2(a.x), flog2(a.y)}; }
static __device__ __forceinline__ v2f max2(v2f a, v2f b) { return (v2f){fmaxf(a.x,b.x), fmaxf(a.y,b.y)}; }

#define EPSF   1e-9f
#define L2E    1.4426950408889634f    // log2(e)
#define LN2    0.6931471805599453f
#define L2_2PI_9 23.86346461225016f   // 9*log2(2*pi)
#define C12F   1.00001e-4f            // (1 - 0.9999) + 1e-9
#define P22F   0.99990001f            // 0.9999 + 1e-9
#define QK     (-0.5f * L2E)

__global__ __launch_bounds__(64, 1)
void kf_kernel(const float* __restrict__ y,      // y[n][t][o]
               const float* __restrict__ pBG, const float* __restrict__ pBT,
               const float* __restrict__ pBB, const float* __restrict__ pBW,
               const float* __restrict__ lam1, const float* __restrict__ lam2,
               const float* __restrict__ qd,  const float* __restrict__ rd,
               const float* __restrict__ pG1, const float* __restrict__ pG2,
               float* __restrict__ partial, int N, int Nt)
{
    const int lane = threadIdx.x;
    const int j    = lane & 3;                     // 0..2 = factor row; 3 = aux
    const int qi   = (blockIdx.x * 64 + lane) >> 2;  // series-PAIR id
    const int sidA = 2 * qi, sidB = 2 * qi + 1;
    const bool vA = (sidA < N), vB = (sidB < N);
    const bool isRow = (j < 3);
    const int jj = isRow ? j : 0;
    const float mrow = isRow ? 1.f : 0.f;          // lane-3 zero mask for constants
    const int rowlen = Nt * 9;                     // 576
    const int nchunk = Nt / 4;

    // ---- wave-uniform setup ----
    const float bg = pBG[0], bt = pBT[0], bb = pBB[0], bw = pBW[0];
    float a[9], l2v[9], id[9], ld[9];
    a[0] = 1.f; a[1] = lam1[0]; a[2] = lam1[1];
    a[3] = 1.f; a[4] = lam1[2]; a[5] = lam1[3];
    a[6] = 1.f; a[7] = lam1[4]; a[8] = lam1[5];
    l2v[0] = 1.f;
    #pragma unroll
    for (int i = 0; i < 8; ++i) l2v[i + 1] = lam2[i];
    float l2detD = 0.f;
    #pragma unroll
    for (int o = 0; o < 9; ++o) {
        float dv = fabsf(rd[o]) + 1.0e-4f + 1.0e-5f;   // R diag + jitter
        id[o] = 1.0f / dv;
        ld[o] = l2v[o] * id[o];
        l2detD += flog2(dv);
    }
    const float q0 = fabsf(qd[0]) + 1e-4f, q1 = fabsf(qd[1]) + 1e-4f;
    const float q2 = fabsf(qd[2]) + 1e-4f, q3 = fabsf(qd[3]) + 1e-4f;
    const float g0 = a[0]*a[0]*id[0] + a[1]*a[1]*id[1] + a[2]*a[2]*id[2];
    const float g1 = a[3]*a[3]*id[3] + a[4]*a[4]*id[4] + a[5]*a[5]*id[5];
    const float g2 = a[6]*a[6]*id[6] + a[7]*a[7]*id[7] + a[8]*a[8]*id[8];
    float h = 0.f;
    #pragma unroll
    for (int o = 0; o < 9; ++o) h += l2v[o] * ld[o];
    const float pk0 = q0 / (1.f + q0 * g0);
    const float pk1 = q1 / (1.f + q1 * g1);
    const float pk2 = q2 / (1.f + q2 * g2);
    const float C12D = C12F * frsq((1.f + q0*g0) * (1.f + q1*g1) * (1.f + q2*g2));
    const float gam1 = pG1[0], w0c = pG2[0], w1c = pG2[1], w2c = pG2[2];
    const float CC = -0.5f * (l2detD + L2_2PI_9);

    // ---- per-lane selected constants; lane 3 masked to 0 so that all of its
    // quad-sum contributions are exactly 0.0f (replaces per-step z3 masks) ----
    auto sel3 = [&](float x0, float x1, float x2) {
        float r = (jj == 1) ? x1 : x0;
        return (jj == 2) ? x2 : r;
    };
    const float aO0 = sel3(a[0], a[3], a[6]), aO1 = sel3(a[1], a[4], a[7]), aO2 = sel3(a[2], a[5], a[8]);
    const float iO0 = sel3(id[0], id[3], id[6]) * mrow, iO1 = sel3(id[1], id[4], id[7]) * mrow,
                iO2 = sel3(id[2], id[5], id[8]) * mrow;
    const float lO0 = sel3(ld[0], ld[3], ld[6]) * mrow, lO1 = sel3(ld[1], ld[4], ld[7]) * mrow,
                lO2 = sel3(ld[2], ld[5], ld[8]) * mrow;
    const float bS = sel3(bg, bt, bb) * mrow;
    const float bS2 = bS * bS;
    const float bSN = bS * sel3(bt, bb, bg);
    const float bSP = bS * sel3(bb, bg, bt);
    const float gS = sel3(g0, g1, g2), gN = sel3(g1, g2, g0), gP = sel3(g2, g0, g1);
    const float qS  = sel3(q0, q1, q2) * mrow;
    const float pkS = sel3(pk0, pk1, pk2) * mrow;
    const float wS  = sel3(w0c, w1c, w2c) * mrow;

    // ---- packed state (x = series A, y = series B) ----
    v2f pf1 = sp(0.99f + EPSF), pf2 = sp(0.01f + EPSF);
    v2f seJ = sp(0.f);
    v2f Pr0 = sp(isRow ? 1000.f : 0.f), Pr1 = sp(0.f), Pr2 = sp(0.f);
    v2f sm2 = sp(0.f), sp2 = sp(1e-9f);
    v2f acc2 = sp(0.f);

    // ---- staging: each lane reads its 3-obs triplet for both series ----
    const float* rowA = y + (size_t)(vA ? sidA : 0) * rowlen + 3 * jj;
    const float* rowB = y + (size_t)(vB ? sidB : 0) * rowlen + 3 * jj;
    v2f A[12], B[12];
    auto loadChunk = [&](v2f (&buf)[12], int c) {
        const float* pA = rowA + c * 36;
        const float* pB = rowB + c * 36;
        #pragma unroll
        for (int s = 0; s < 4; ++s) {
            #pragma unroll
            for (int k = 0; k < 3; ++k) {
                buf[s*3+k].x = pA[s*9+k];
                buf[s*3+k].y = pB[s*9+k];
            }
        }
    };
    loadChunk(A, 0);

    auto step4 = [&](const v2f (&buf)[12]) {
        #pragma unroll
        for (int s = 0; s < 4; ++s) {
            const v2f y0 = buf[s*3+0], y1 = buf[s*3+1], y2 = buf[s*3+2];

            // HMM transition (logit allreduced; sigmoid dup)
            v2f logit = sp(gam1) + qsum2(sp(wS) * seJ);
            v2f esig = exp22(logit * sp(-L2E));
            v2f p11 = rcp2(sp(1.f) + esig);
            v2f pf11 = p11 + sp(EPSF);
            v2f pf21 = sp(1.f) - p11 + sp(EPSF);

            // prediction: mean comp j, S row j (relative), M row j
            v2f epJ = sp(bS) * seJ;
            v2f S0 = sp(bS2) * Pr0 + sp(qS);
            v2f S1 = sp(bSN) * Pr1;
            v2f S2 = sp(bSP) * Pr2;
            v2f M0 = S0 * sp(gS) + sp(1.f);
            v2f M1 = S1 * sp(gN);
            v2f M2 = S2 * sp(gP);

            // innovation on own obs triplet
            v2f v0 = y0 - sp(aO0)*epJ;
            v2f v1 = y1 - sp(aO1)*epJ;
            v2f v2 = y2 - sp(aO2)*epJ;
            v2f w0 = sp(iO0)*v0, w1 = sp(iO1)*v1, w2 = sp(iO2)*v2;
            v2f uJ = sp(aO0)*w0 + sp(aO1)*w1 + sp(aO2)*w2;
            v2f r1 = v0*w0 + v1*w1 + v2*w2;        // local v.w (lane3 = 0)
            v2f yl  = qsum2(sp(lO0)*y0 + sp(lO1)*y1 + sp(lO2)*y2);
            v2f ydy = qsum2(r1 + epJ*(sp(2.f)*uJ + sp(gS)*epJ));

            // 3x3: gather other M rows, cross-product cofactor row, local det
            v2f Mn0 = dpp2<ROTL>(M0), Mn1 = dpp2<ROTL>(M1), Mn2 = dpp2<ROTL>(M2);
            v2f Mp0 = dpp2<ROTR>(M0), Mp1 = dpp2<ROTR>(M1), Mp2 = dpp2<ROTR>(M2);
            v2f cf0 = Mn0*Mp0 - Mn1*Mp2;
            v2f cf1 = Mn1*Mp1 - Mn2*Mp0;
            v2f cf2 = Mn2*Mp2 - Mn0*Mp1;
            v2f det = M0*cf0 + M1*cf1 + M2*cf2;    // det(M) >= 1; lane3: det = 1
            v2f rs  = rsq2(det);
            v2f iM  = rs * rs;                     // 1/det
            v2f cn0 = dpp2<ROTL>(cf0), cn1 = dpp2<ROTL>(cf1), cn2 = dpp2<ROTL>(cf2);
            v2f cp0 = dpp2<ROTR>(cf0), cp1 = dpp2<ROTR>(cf1), cp2 = dpp2<ROTR>(cf2);
            // Ci row j = (S * cof) row j / det  (N = S*cof symmetric)
            v2f Ci0 = iM * (S0*cf0 + S1*cn2 + S2*cp1);
            v2f Ci1 = iM * (S0*cf1 + S1*cn0 + S2*cp2);
            v2f Ci2 = iM * (S0*cf2 + S1*cn1 + S2*cp0);

            // t = Ci u ; quad11 merged with the v.w reduction (one qsum)
            v2f uN = dpp2<ROTL>(uJ), uP = dpp2<ROTR>(uJ);
            v2f tJ = Ci0*uJ + Ci1*uN + Ci2*uP;
            v2f quad11 = qsum2(r1 - uJ*tJ);
            v2f euJ = epJ + tJ;

            // branch 12 (constant prior)
            v2f u12 = uJ + sp(gS)*epJ;
            v2f fJ  = sp(pkS) * u12;
            v2f quad12 = ydy - qsum2(sp(pkS)*u12*u12);

            // regime-2 twin: branch 21 (_1) / 22 (_2), rank-1 Sherman-Morrison
            v2f seS = qsum2(seJ);
            v2f sP  = qsum2(Pr0 + Pr1 + Pr2);
            v2f m2_1 = seS * sp(1.f/3.f);
            v2f m2_2 = sp(bw) * sm2;
            v2f pv_1 = sp(q3) + sP * sp(1.f/9.f);
            v2f pv_2 = sp(bw*bw)*sp2 + sp(q3);
            v2f u1_1 = yl - m2_1*sp(h);
            v2f u1_2 = yl - m2_2*sp(h);
            v2f vda_1 = ydy - m2_1*(sp(2.f)*yl - m2_1*sp(h));
            v2f vda_2 = ydy - m2_2*(sp(2.f)*yl - m2_2*sp(h));
            v2f den_1 = sp(1.f) + pv_1*sp(h);
            v2f den_2 = sp(1.f) + pv_2*sp(h);
            v2f rv_1 = rsq2(den_1), rv_2 = rsq2(den_2);
            v2f pu_1 = pv_1*(rv_1*rv_1), pu_2 = pv_2*(rv_2*rv_2);
            v2f quad21 = vda_1 - pu_1*u1_1*u1_1;
            v2f quad22 = vda_2 - pu_2*u1_2*u1_2;
            v2f eu_1 = m2_1 + pu_1*u1_1;
            v2f eu_2 = m2_2 + pu_2*u1_2;

            // mixing (dup across quad; dets folded via rsq factors)
            v2f q11e = sp(QK)*quad11, q12e = sp(QK)*quad12;
            v2f q21e = sp(QK)*quad21, q22e = sp(QK)*quad22;
            v2f Mq = max2(max2(q11e, q12e), max2(q21e, q22e));
            v2f w11 = pf1*pf11*rs        * exp22(q11e - Mq);
            v2f w12 = pf2*sp(C12D)       * exp22(q12e - Mq);
            v2f w21 = pf1*pf21*rv_1      * exp22(q21e - Mq);
            v2f w22 = pf2*sp(P22F)*rv_2  * exp22(q22e - Mq);
            v2f ssum = w11 + w12 + w21 + w22;
            acc2 += Mq + log22(ssum);
            v2f pr1n = w11 + w12, pr2n = w21 + w22;
            v2f den1 = pr1n + sp(EPSF)*ssum, den2 = pr2n + sp(EPSF)*ssum;
            v2f inv1 = rcp2(den1), inv2 = rcp2(den2), issum = rcp2(ssum);
            v2f W11 = w11*inv1, W12 = w12*inv1;
            v2f W21 = w21*inv2, W22 = w22*inv2;
            pf1 = pr1n*issum + sp(EPSF);
            pf2 = pr2n*issum + sp(EPSF);

            // collapse regime 1 (row form)
            v2f neJ = W11*euJ + W12*fJ;
            v2f daJ = euJ - neJ, dbJ = fJ - neJ;
            v2f daN = dpp2<ROTL>(daJ), daP = dpp2<ROTR>(daJ);
            v2f dbN = dpp2<ROTL>(dbJ), dbP = dpp2<ROTR>(dbJ);
            Pr0 = W11*(Ci0 + daJ*daJ) + W12*(sp(pkS) + dbJ*dbJ);
            Pr1 = W11*(Ci1 + daJ*daN) + W12*(dbJ*dbN);
            Pr2 = W11*(Ci2 + daJ*daP) + W12*(dbJ*dbP);
            seJ = neJ;

            // collapse regime 2 (dup)
            v2f nm2 = W21*eu_1 + W22*eu_2;
            v2f dc = eu_1 - nm2, dd = eu_2 - nm2;
            sp2 = W21*(pu_1 + dc*dc) + W22*(pu_2 + dd*dd);
            sm2 = nm2;
        }
    };

    for (int c = 0; c < nchunk; c += 2) {
        if (c + 1 < nchunk) loadChunk(B, c + 1);
        step4(A);
        if (c + 2 < nchunk) loadChunk(A, c + 2);
        step4(B);
    }

    // two results per quad (sublane 0 holds both halves), wave-reduce
    float acc = 0.f;
    if (j == 0) {
        if (vA) acc += (acc2.x + (float)Nt * CC) * LN2;
        if (vB) acc += (acc2.y + (float)Nt * CC) * LN2;
    }
    #pragma unroll
    for (int off = 32; off; off >>= 1) acc += __shfl_down(acc, off, 64);
    if (lane == 0) partial[blockIdx.x] = acc;
}

__global__ __launch_bounds__(64)
void reduce_k(const float* __restrict__ part, float* __restrict__ out, int nb)
{
    float s = 0.f;
    for (int i = threadIdx.x; i < nb; i += 64) s += part[i];
    #pragma unroll
    for (int off = 32; off; off >>= 1) s += __shfl_down(s, off, 64);
    if (threadIdx.x == 0) out[0] = s;
}

extern "C" void kernel_launch(void* const* d_in, const int* in_sizes, int n_in,
                              void* d_out, int out_size, void* d_ws, size_t ws_size,
                              hipStream_t stream)
{
    const float* y    = (const float*)d_in[0];
    const float* pBG  = (const float*)d_in[1];
    const float* pBT  = (const float*)d_in[2];
    const float* pBB  = (const float*)d_in[3];
    const float* pBW  = (const float*)d_in[4];
    const float* lam1 = (const float*)d_in[5];
    const float* lam2 = (const float*)d_in[6];
    const float* qd   = (const float*)d_in[7];
    const float* rd   = (const float*)d_in[8];
    const float* pG1  = (const float*)d_in[9];
    const float* pG2  = (const float*)d_in[10];

    const int total = in_sizes[0];
    const int Nt = 64, O = 9;
    const int N = total / (Nt * O);
    const int nq = (N + 1) / 2;                  // series pairs
    const int blocks = (nq * 4 + 63) / 64;       // 4 lanes per PAIR

    float* partial = (float*)d_ws;
    kf_kernel<<<blocks, 64, 0, stream>>>(y, pBG, pBT, pBB, pBW, lam1, lam2,
                                         qd, rd, pG1, pG2, partial, N, Nt);
    reduce_k<<<1, 64, 0, stream>>>(partial, (float*)d_out, blocks);
}

// Round 4
// 130.424 us; speedup vs baseline: 1.0207x; 1.0207x over previous
//
#include <hip/hip_runtime.h>

// Regime-switching KF — PER-LANE FULL-SCALAR: 1 series per lane, 64 series
// per wave, 256 waves. No cross-lane ops at all (no DPP, no qsum): each lane
// runs the complete optimized step for its own series. Rationale (R3
// post-mortem): both quad (1673 cyc/step, 51% per-SIMD busy) and packed-pair
// (1950 cyc/step, 51%) fit wall = I x 4cyc x 64 steps — single-wave
// dependent-issue cadence with ILP~1. Wall time is per-wave serial time
// (parallelism surplus), so the only lever is wave-insts/step. Per-lane
// scalar removes lane-3 waste, regime-2 x4 duplication, and ~32 DPPs/step
// (VALU->DPP hazards) — ~290 insts/step covering 64 series vs ~435 covering
// 16. All algebraic tricks ported: diagonal-G determinant lemma
// (det F = det D * det(I+SG)), symmetric-P 6-entry updates, cofactor 3x3
// with rsq-folded det^(-1/2), Sherman-Morrison regime-2, log2-domain mixing.

static __device__ __forceinline__ float frcp(float x)  { return __builtin_amdgcn_rcpf(x); }
static __device__ __forceinline__ float frsq(float x)  { return __builtin_amdgcn_rsqf(x); }
static __device__ __forceinline__ float fexp2(float x) { return __builtin_amdgcn_exp2f(x); }
static __device__ __forceinline__ float flog2(float x) { return __builtin_amdgcn_logf(x); }

#define EPSF   1e-9f
#define L2E    1.4426950408889634f    // log2(e)
#define LN2    0.6931471805599453f
#define L2_2PI_9 23.86346461225016f   // 9*log2(2*pi)
#define C12F   1.00001e-4f            // (1 - 0.9999) + 1e-9
#define P22F   0.99990001f            // 0.9999 + 1e-9
#define QK     (-0.5f * L2E)

__global__ __launch_bounds__(64, 1)
void kf_kernel(const float* __restrict__ y,      // y[n][t][o]
               const float* __restrict__ pBG, const float* __restrict__ pBT,
               const float* __restrict__ pBB, const float* __restrict__ pBW,
               const float* __restrict__ lam1, const float* __restrict__ lam2,
               const float* __restrict__ qd,  const float* __restrict__ rd,
               const float* __restrict__ pG1, const float* __restrict__ pG2,
               float* __restrict__ partial, int N, int Nt)
{
    const int lane = threadIdx.x;
    const int sid  = blockIdx.x * 64 + lane;      // one series per lane
    const bool valid = (sid < N);
    const int rowlen = Nt * 9;                    // 576

    // ---- wave-uniform setup (lands in SGPRs) ----
    const float bg = pBG[0], bt = pBT[0], bb = pBB[0], bw = pBW[0];
    const float a1 = lam1[0], a2 = lam1[1];
    const float a4 = lam1[2], a5 = lam1[3];
    const float a7 = lam1[4], a8 = lam1[5];
    float l2v[9], id[9], ld[9];
    l2v[0] = 1.f;
    #pragma unroll
    for (int i = 0; i < 8; ++i) l2v[i + 1] = lam2[i];
    float l2detD = 0.f;
    #pragma unroll
    for (int o = 0; o < 9; ++o) {
        float dv = fabsf(rd[o]) + 1.0e-4f + 1.0e-5f;   // R diag + jitter
        id[o] = 1.0f / dv;
        ld[o] = l2v[o] * id[o];
        l2detD += flog2(dv);
    }
    const float id0 = id[0], id1 = id[1], id2 = id[2],
                id3 = id[3], id4 = id[4], id5 = id[5],
                id6 = id[6], id7 = id[7], id8 = id[8];
    const float ld0 = ld[0], ld1 = ld[1], ld2 = ld[2],
                ld3 = ld[3], ld4 = ld[4], ld5 = ld[5],
                ld6 = ld[6], ld7 = ld[7], ld8 = ld[8];
    const float aid0 = id0,      aid1 = a1 * id1, aid2 = a2 * id2;
    const float aid3 = id3,      aid4 = a4 * id4, aid5 = a5 * id5;
    const float aid6 = id6,      aid7 = a7 * id7, aid8 = a8 * id8;
    const float q0 = fabsf(qd[0]) + 1e-4f, q1 = fabsf(qd[1]) + 1e-4f;
    const float q2 = fabsf(qd[2]) + 1e-4f, q3 = fabsf(qd[3]) + 1e-4f;
    const float g0 = id0 + a1*a1*id1 + a2*a2*id2;
    const float g1 = id3 + a4*a4*id4 + a5*a5*id5;
    const float g2 = id6 + a7*a7*id7 + a8*a8*id8;
    float h = 0.f;
    #pragma unroll
    for (int o = 0; o < 9; ++o) h += l2v[o] * ld[o];
    const float pk0 = q0 / (1.f + q0 * g0);
    const float pk1 = q1 / (1.f + q1 * g1);
    const float pk2 = q2 / (1.f + q2 * g2);
    const float C12D = C12F * frsq((1.f + q0*g0) * (1.f + q1*g1) * (1.f + q2*g2));
    const float gam1 = pG1[0], w0c = pG2[0], w1c = pG2[1], w2c = pG2[2];
    const float CC = -0.5f * (l2detD + L2_2PI_9);
    const float bg2 = bg*bg, bt2 = bt*bt, bb2 = bb*bb, bw2 = bw*bw;
    const float bgbt = bg*bt, bgbb = bg*bb, btbb = bt*bb;

    // ---- per-series state (all registers) ----
    float pf1 = 0.99f + EPSF, pf2 = 0.01f + EPSF;
    float se0 = 0.f, se1 = 0.f, se2 = 0.f;
    float p00 = 1000.f, p01 = 0.f, p02 = 0.f, p11 = 1000.f, p12 = 0.f, p22 = 1000.f;
    float sm2 = 0.f, sp2 = 1e-9f;
    float acc2 = 0.f;

    const float* row = y + (size_t)(valid ? sid : 0) * rowlen;
    float A[9], B[9];
    #pragma unroll
    for (int k = 0; k < 9; ++k) A[k] = row[k];

    auto step = [&](const float (&Y)[9]) {
        // HMM transition
        float logit = gam1 + w0c*se0 + w1c*se1 + w2c*se2;
        float p11s = frcp(1.f + fexp2(-logit * L2E));
        float pf11 = p11s + EPSF, pf21 = 1.f - p11s + EPSF;

        // prediction (regime 1): mean, S = B P B^T + Q (symmetric, 6 entries)
        float e0 = bg*se0, e1 = bt*se1, e2 = bb*se2;
        float s00 = bg2*p00 + q0, s11 = bt2*p11 + q1, s22 = bb2*p22 + q2;
        float s01 = bgbt*p01, s02 = bgbb*p02, s12 = btbb*p12;

        // innovations, u = A^T D^-1 v (block structure: 3 obs per factor)
        float v0 = Y[0] - e0,    v1 = Y[1] - a1*e0, v2 = Y[2] - a2*e0;
        float v3 = Y[3] - e1,    v4 = Y[4] - a4*e1, v5 = Y[5] - a5*e1;
        float v6 = Y[6] - e2,    v7 = Y[7] - a7*e2, v8 = Y[8] - a8*e2;
        float u0 = aid0*v0 + aid1*v1 + aid2*v2;
        float u1 = aid3*v3 + aid4*v4 + aid5*v5;
        float u2 = aid6*v6 + aid7*v7 + aid8*v8;
        float vdv = (id0*v0)*v0 + (id1*v1)*v1 + (id2*v2)*v2
                  + (id3*v3)*v3 + (id4*v4)*v4 + (id5*v5)*v5
                  + (id6*v6)*v6 + (id7*v7)*v7 + (id8*v8)*v8;
        float yl  = ld0*Y[0] + ld1*Y[1] + ld2*Y[2]
                  + ld3*Y[3] + ld4*Y[4] + ld5*Y[5]
                  + ld6*Y[6] + ld7*Y[7] + ld8*Y[8];
        // ydy = y^T D^-1 y = vdv + e.(2u + G e)   (G diagonal)
        float k0 = 2.f*u0 + g0*e0, k1 = 2.f*u1 + g1*e1, k2 = 2.f*u2 + g2*e2;
        float ydy = vdv + e0*k0 + e1*k1 + e2*k2;

        // M = I + S*diag(g); cofactors; det; Ci = S*C/det (posterior cov, sym)
        float m00 = s00*g0 + 1.f, m01 = s01*g1,       m02 = s02*g2;
        float m10 = s01*g0,       m11 = s11*g1 + 1.f, m12 = s12*g2;
        float m20 = s02*g0,       m21 = s12*g1,       m22 = s22*g2 + 1.f;
        float c00 = m11*m22 - m12*m21;
        float c01 = m12*m20 - m10*m22;
        float c02 = m10*m21 - m11*m20;
        float c10 = m02*m21 - m01*m22;
        float c11 = m00*m22 - m02*m20;
        float c12 = m01*m20 - m00*m21;
        float c20 = m01*m12 - m02*m11;
        float c21 = m02*m10 - m00*m12;
        float c22 = m00*m11 - m01*m10;
        float det = m00*c00 + m01*c01 + m02*c02;   // det(M) >= 1
        float rs  = frsq(det);
        float iM  = rs * rs;                        // 1/det
        float Ci00 = (s00*c00 + s01*c10 + s02*c20) * iM;
        float Ci01 = (s00*c01 + s01*c11 + s02*c21) * iM;
        float Ci02 = (s00*c02 + s01*c12 + s02*c22) * iM;
        float Ci11 = (s01*c01 + s11*c11 + s12*c21) * iM;
        float Ci12 = (s01*c02 + s11*c12 + s12*c22) * iM;
        float Ci22 = (s02*c02 + s12*c12 + s22*c22) * iM;

        // branch 11: t = Ci u; quad11 = vdv - u.t; posterior mean
        float t0 = Ci00*u0 + Ci01*u1 + Ci02*u2;
        float t1 = Ci01*u0 + Ci11*u1 + Ci12*u2;
        float t2 = Ci02*u0 + Ci12*u1 + Ci22*u2;
        float quad11 = vdv - (u0*t0 + u1*t1 + u2*t2);
        float eu0 = e0 + t0, eu1 = e1 + t1, eu2 = e2 + t2;

        // branch 12 (constant diagonal prior Q): u12 = A^T D^-1 y per factor
        float u120 = u0 + g0*e0, u121 = u1 + g1*e1, u122 = u2 + g2*e2;
        float f0 = pk0*u120, f1 = pk1*u121, f2 = pk2*u122;
        float quad12 = ydy - (f0*u120 + f1*u121 + f2*u122);

        // regime-2 twin: branches 21/22, rank-1 Sherman-Morrison
        float seS = se0 + se1 + se2;
        float sPs = p00 + p11 + p22 + 2.f*(p01 + p02 + p12);
        float m2a = seS * (1.f/3.f);
        float m2b = bw * sm2;
        float pva = q3 + sPs * (1.f/9.f);
        float pvb = bw2*sp2 + q3;
        float u1a = yl - m2a*h;
        float u1b = yl - m2b*h;
        float vdaa = ydy - m2a*(2.f*yl - m2a*h);
        float vdab = ydy - m2b*(2.f*yl - m2b*h);
        float rva = frsq(1.f + pva*h);
        float rvb = frsq(1.f + pvb*h);
        float pua = pva*(rva*rva);
        float pub = pvb*(rvb*rvb);
        float quad21 = vdaa - pua*u1a*u1a;
        float quad22 = vdab - pub*u1b*u1b;
        float eua = m2a + pua*u1a;
        float eub = m2b + pub*u1b;

        // mixing (log2 domain; det^(-1/2) folded via rs/rva/rvb factors)
        float q11e = QK*quad11, q12e = QK*quad12;
        float q21e = QK*quad21, q22e = QK*quad22;
        float Mq = fmaxf(fmaxf(q11e, q12e), fmaxf(q21e, q22e));
        float w11 = pf1*pf11*rs   * fexp2(q11e - Mq);
        float w12 = pf2*C12D      * fexp2(q12e - Mq);
        float w21 = pf1*pf21*rva  * fexp2(q21e - Mq);
        float w22 = pf2*P22F*rvb  * fexp2(q22e - Mq);
        float ssum = (w11 + w12) + (w21 + w22);
        acc2 += Mq + flog2(ssum);
        float pr1n = w11 + w12, pr2n = w21 + w22;
        float inv1 = frcp(pr1n + EPSF*ssum);
        float inv2 = frcp(pr2n + EPSF*ssum);
        float issum = frcp(ssum);
        float W11 = w11*inv1, W12 = w12*inv1;
        float W21 = w21*inv2, W22 = w22*inv2;
        pf1 = pr1n*issum + EPSF;
        pf2 = pr2n*issum + EPSF;

        // collapse regime 1 (symmetric P, 6 entries; branch-12 posterior = diag pk)
        float ne0 = W11*eu0 + W12*f0;
        float ne1 = W11*eu1 + W12*f1;
        float ne2 = W11*eu2 + W12*f2;
        float da0 = eu0-ne0, da1 = eu1-ne1, da2 = eu2-ne2;
        float db0 = f0-ne0,  db1 = f1-ne1,  db2 = f2-ne2;
        p00 = W11*(Ci00 + da0*da0) + W12*(pk0 + db0*db0);
        p01 = W11*(Ci01 + da0*da1) + W12*(db0*db1);
        p02 = W11*(Ci02 + da0*da2) + W12*(db0*db2);
        p11 = W11*(Ci11 + da1*da1) + W12*(pk1 + db1*db1);
        p12 = W11*(Ci12 + da1*da2) + W12*(db1*db2);
        p22 = W11*(Ci22 + da2*da2) + W12*(pk2 + db2*db2);
        se0 = ne0; se1 = ne1; se2 = ne2;

        // collapse regime 2
        float nm2 = W21*eua + W22*eub;
        float dc = eua-nm2, dd = eub-nm2;
        sp2 = W21*(pua + dc*dc) + W22*(pub + dd*dd);
        sm2 = nm2;
    };

    for (int t = 0; t < Nt; t += 2) {
        #pragma unroll
        for (int k = 0; k < 9; ++k) B[k] = row[(t+1)*9 + k];
        step(A);
        if (t + 2 < Nt) {
            #pragma unroll
            for (int k = 0; k < 9; ++k) A[k] = row[(t+2)*9 + k];
        }
        step(B);
    }

    // one result per lane; wave-reduce; one partial per block (1 wave/block)
    float acc = valid ? (acc2 + (float)Nt * CC) * LN2 : 0.f;
    #pragma unroll
    for (int off = 32; off; off >>= 1) acc += __shfl_down(acc, off, 64);
    if (lane == 0) partial[blockIdx.x] = acc;
}

__global__ __launch_bounds__(64)
void reduce_k(const float* __restrict__ part, float* __restrict__ out, int nb)
{
    float s = 0.f;
    for (int i = threadIdx.x; i < nb; i += 64) s += part[i];
    #pragma unroll
    for (int off = 32; off; off >>= 1) s += __shfl_down(s, off, 64);
    if (threadIdx.x == 0) out[0] = s;
}

extern "C" void kernel_launch(void* const* d_in, const int* in_sizes, int n_in,
                              void* d_out, int out_size, void* d_ws, size_t ws_size,
                              hipStream_t stream)
{
    const float* y    = (const float*)d_in[0];
    const float* pBG  = (const float*)d_in[1];
    const float* pBT  = (const float*)d_in[2];
    const float* pBB  = (const float*)d_in[3];
    const float* pBW  = (const float*)d_in[4];
    const float* lam1 = (const float*)d_in[5];
    const float* lam2 = (const float*)d_in[6];
    const float* qd   = (const float*)d_in[7];
    const float* rd   = (const float*)d_in[8];
    const float* pG1  = (const float*)d_in[9];
    const float* pG2  = (const float*)d_in[10];

    const int total = in_sizes[0];
    const int Nt = 64, O = 9;
    const int N = total / (Nt * O);
    const int blocks = (N + 63) / 64;            // 1 series per lane

    float* partial = (float*)d_ws;
    kf_kernel<<<blocks, 64, 0, stream>>>(y, pBG, pBT, pBB, pBW, lam1, lam2,
                                         qd, rd, pG1, pG2, partial, N, Nt);
    reduce_k<<<1, 64, 0, stream>>>(partial, (float*)d_out, blocks);
}

// Round 5
// 127.576 us; speedup vs baseline: 1.0435x; 1.0223x over previous
//
#include <hip/hip_runtime.h>

// Regime-switching KF — PER-LANE SCALAR v2: 1 series/lane, 64 series/wave,
// 256 waves. R4 post-mortem: wall = per-wave serial time (1 wave/SIMD,
// dependent-chain bound). v2 cuts wave-insts/step ~20% AND moves ~35
// insts/step off the serial path into freely-schedulable input-only work:
//   (1) uy-restructure: u = uy - G e with uy = A^T D^-1 y (input-only);
//       vdv = ydy - e.(uy+u); branch-12's u12 == uy so f = pk*uy and
//       quad12/q12e are input-only too -> all hoisted to a Y-block
//       computed one step AHEAD (fills the 3x3 chain's stall slots).
//   (2) iM-late: SC = S*adj(M) unnormalized; 1/det folded into t, quad11,
//       and W11i = W11/det at collapse -> det/rsq off the critical path.
//   (3) regime-2 twin as v2f (R3-proven packed form).
// Algebra verified: u12=uy, vdv fold, Ci = SC/det symmetric, det(F) =
// det(D)*det(M) lemma unchanged.

typedef float v2f __attribute__((ext_vector_type(2)));
typedef v2f v2fu __attribute__((aligned(4)));

static __device__ __forceinline__ float frcp(float x)  { return __builtin_amdgcn_rcpf(x); }
static __device__ __forceinline__ float frsq(float x)  { return __builtin_amdgcn_rsqf(x); }
static __device__ __forceinline__ float fexp2(float x) { return __builtin_amdgcn_exp2f(x); }
static __device__ __forceinline__ float flog2(float x) { return __builtin_amdgcn_logf(x); }
static __device__ __forceinline__ v2f sp(float x) { return (v2f){x, x}; }
static __device__ __forceinline__ v2f rsq2(v2f a) { return (v2f){frsq(a.x), frsq(a.y)}; }

#define EPSF   1e-9f
#define L2E    1.4426950408889634f    // log2(e)
#define LN2    0.6931471805599453f
#define L2_2PI_9 23.86346461225016f   // 9*log2(2*pi)
#define C12F   1.00001e-4f            // (1 - 0.9999) + 1e-9
#define P22F   0.99990001f            // 0.9999 + 1e-9
#define QK     (-0.5f * L2E)

__global__ __launch_bounds__(64, 1)
void kf_kernel(const float* __restrict__ y,      // y[n][t][o]
               const float* __restrict__ pBG, const float* __restrict__ pBT,
               const float* __restrict__ pBB, const float* __restrict__ pBW,
               const float* __restrict__ lam1, const float* __restrict__ lam2,
               const float* __restrict__ qd,  const float* __restrict__ rd,
               const float* __restrict__ pG1, const float* __restrict__ pG2,
               float* __restrict__ partial, int N, int Nt)
{
    const int lane = threadIdx.x;
    const int sid  = blockIdx.x * 64 + lane;      // one series per lane
    const bool valid = (sid < N);
    const int rowlen = Nt * 9;                    // 576

    // ---- wave-uniform setup ----
    const float bg = pBG[0], bt = pBT[0], bb = pBB[0], bw = pBW[0];
    const float a1 = lam1[0], a2 = lam1[1];
    const float a4 = lam1[2], a5 = lam1[3];
    const float a7 = lam1[4], a8 = lam1[5];
    float l2v[9], id[9], ld[9];
    l2v[0] = 1.f;
    #pragma unroll
    for (int i = 0; i < 8; ++i) l2v[i + 1] = lam2[i];
    float l2detD = 0.f;
    #pragma unroll
    for (int o = 0; o < 9; ++o) {
        float dv = fabsf(rd[o]) + 1.0e-4f + 1.0e-5f;   // R diag + jitter
        id[o] = 1.0f / dv;
        ld[o] = l2v[o] * id[o];
        l2detD += flog2(dv);
    }
    const float id8 = id[8], ld8 = ld[8];
    const v2f idv01 = {id[0], id[1]}, idv23 = {id[2], id[3]},
              idv45 = {id[4], id[5]}, idv67 = {id[6], id[7]};
    const v2f ldv01 = {ld[0], ld[1]}, ldv23 = {ld[2], ld[3]},
              ldv45 = {ld[4], ld[5]}, ldv67 = {ld[6], ld[7]};
    const float aid0 = id[0],    aid1 = a1*id[1], aid2 = a2*id[2];
    const float aid3 = id[3],    aid4 = a4*id[4], aid5 = a5*id[5];
    const float aid6 = id[6],    aid7 = a7*id[7], aid8 = a8*id[8];
    const float q0 = fabsf(qd[0]) + 1e-4f, q1 = fabsf(qd[1]) + 1e-4f;
    const float q2 = fabsf(qd[2]) + 1e-4f, q3 = fabsf(qd[3]) + 1e-4f;
    const float g0 = id[0] + a1*a1*id[1] + a2*a2*id[2];
    const float g1 = id[3] + a4*a4*id[4] + a5*a5*id[5];
    const float g2 = id[6] + a7*a7*id[7] + a8*a8*id[8];
    float h = 0.f;
    #pragma unroll
    for (int o = 0; o < 9; ++o) h += l2v[o] * ld[o];
    const float pk0 = q0 / (1.f + q0 * g0);
    const float pk1 = q1 / (1.f + q1 * g1);
    const float pk2 = q2 / (1.f + q2 * g2);
    const float C12D = C12F * frsq((1.f + q0*g0) * (1.f + q1*g1) * (1.f + q2*g2));
    const float gam1 = pG1[0], w0c = pG2[0], w1c = pG2[1], w2c = pG2[2];
    const float CC = -0.5f * (l2detD + L2_2PI_9);
    const float bg2 = bg*bg, bt2 = bt*bt, bb2 = bb*bb, bw2 = bw*bw;
    const float bgbt = bg*bt, bgbb = bg*bb, btbb = bt*bb;
    const v2f hv = {h, h};

    // ---- per-series state ----
    float pf1 = 0.99f + EPSF, pf2 = 0.01f + EPSF;
    float se0 = 0.f, se1 = 0.f, se2 = 0.f;
    float p00 = 1000.f, p01 = 0.f, p02 = 0.f, p11 = 1000.f, p12 = 0.f, p22 = 1000.f;
    float sm2 = 0.f, sp2 = 1e-9f;
    float acc2 = 0.f;

    struct Yr { v2f ab, cd, ef, gh; float i8; };
    struct YB { float uy0, uy1, uy2, yl, ydy, f0, f1, f2, q12e; };

    const char* rowb = (const char*)(y + (size_t)(valid ? sid : 0) * rowlen);
    auto loadY = [&](Yr& r, int t) {
        const char* p = rowb + t * 36;
        r.ab = *(const v2fu*)(p);
        r.cd = *(const v2fu*)(p + 8);
        r.ef = *(const v2fu*)(p + 16);
        r.gh = *(const v2fu*)(p + 24);
        r.i8 = *(const float*)(p + 32);
    };
    // pure function of the observation row -> freely schedulable filler
    auto computeYB = [&](const Yr& r) {
        YB o;
        v2f m0 = idv01*r.ab, m1 = idv23*r.cd, m2 = idv45*r.ef, m3 = idv67*r.gh;
        v2f yq = m0*r.ab + m1*r.cd + m2*r.ef + m3*r.gh;
        o.ydy = fmaf(id8*r.i8, r.i8, yq.x + yq.y);
        v2f la = ldv01*r.ab + ldv23*r.cd + ldv45*r.ef + ldv67*r.gh;
        o.yl = fmaf(ld8, r.i8, la.x + la.y);
        o.uy0 = fmaf(aid2, r.cd.x, fmaf(aid1, r.ab.y, aid0*r.ab.x));
        o.uy1 = fmaf(aid5, r.ef.y, fmaf(aid4, r.ef.x, aid3*r.cd.y));
        o.uy2 = fmaf(aid8, r.i8,   fmaf(aid7, r.gh.y, aid6*r.gh.x));
        o.f0 = pk0*o.uy0; o.f1 = pk1*o.uy1; o.f2 = pk2*o.uy2;
        o.q12e = QK * (o.ydy - (o.f0*o.uy0 + o.f1*o.uy1 + o.f2*o.uy2));
        return o;
    };

    auto step = [&](const YB& yb) {
        // HMM transition (early; off critical path)
        float logit = fmaf(w2c, se2, fmaf(w1c, se1, fmaf(w0c, se0, gam1)));
        float p11s = frcp(1.f + fexp2(-L2E * logit));
        float pp1 = pf1 * (p11s + EPSF);
        float pp2 = pf1 * (1.f - p11s + EPSF);

        // prediction (regime 1): S = B P B^T + Q (symmetric)
        float e0 = bg*se0, e1 = bt*se1, e2 = bb*se2;
        float s00 = fmaf(bg2, p00, q0), s11 = fmaf(bt2, p11, q1), s22 = fmaf(bb2, p22, q2);
        float s01 = bgbt*p01, s02 = bgbb*p02, s12 = btbb*p12;

        // u = uy - G e ; vdv = ydy - e.(uy+u)
        float u0 = fmaf(-g0, e0, yb.uy0);
        float u1 = fmaf(-g1, e1, yb.uy1);
        float u2 = fmaf(-g2, e2, yb.uy2);
        float vdv = yb.ydy - (e0*(yb.uy0+u0) + e1*(yb.uy1+u1) + e2*(yb.uy2+u2));

        // M = I + S*diag(g); cofactors; det; SC = S*adj(M) (iM folded late)
        float m00 = fmaf(s00, g0, 1.f), m11 = fmaf(s11, g1, 1.f), m22 = fmaf(s22, g2, 1.f);
        float m01 = s01*g1, m02 = s02*g2;
        float m10 = s01*g0, m20 = s02*g0;
        float m12 = s12*g2, m21 = s12*g1;
        float c00 = fmaf(m11, m22, -m12*m21);
        float c01 = fmaf(m12, m20, -m10*m22);
        float c02 = fmaf(m10, m21, -m11*m20);
        float c10 = fmaf(m02, m21, -m01*m22);
        float c11 = fmaf(m00, m22, -m02*m20);
        float c12 = fmaf(m01, m20, -m00*m21);
        float c20 = fmaf(m01, m12, -m02*m11);
        float c21 = fmaf(m02, m10, -m00*m12);
        float c22 = fmaf(m00, m11, -m01*m10);
        float det = fmaf(m02, c02, fmaf(m01, c01, m00*c00));   // >= 1
        float rs  = frsq(det);
        float iM  = rs * rs;                                   // 1/det
        float SC00 = fmaf(s02, c20, fmaf(s01, c10, s00*c00));
        float SC01 = fmaf(s02, c21, fmaf(s01, c11, s00*c01));
        float SC02 = fmaf(s02, c22, fmaf(s01, c12, s00*c02));
        float SC11 = fmaf(s12, c21, fmaf(s11, c11, s01*c01));
        float SC12 = fmaf(s12, c22, fmaf(s11, c12, s01*c02));
        float SC22 = fmaf(s22, c22, fmaf(s12, c12, s02*c02));

        // branch 11: n = SC u; quad11 = vdv - (u.n)/det; eu = e + n/det
        float n0 = fmaf(SC02, u2, fmaf(SC01, u1, SC00*u0));
        float n1 = fmaf(SC12, u2, fmaf(SC11, u1, SC01*u0));
        float n2 = fmaf(SC22, u2, fmaf(SC12, u1, SC02*u0));
        float un = fmaf(u2, n2, fmaf(u1, n1, u0*n0));
        float quad11 = fmaf(-iM, un, vdv);
        float eu0 = fmaf(iM, n0, e0), eu1 = fmaf(iM, n1, e1), eu2 = fmaf(iM, n2, e2);

        // regime-2 twin (packed a=branch21, b=branch22): Sherman-Morrison
        float seS = se0 + se1 + se2;
        float sPs = fmaf(2.f, (p01 + p02) + p12, (p00 + p11) + p22);
        v2f m2v; m2v.x = seS * (1.f/3.f);          m2v.y = bw * sm2;
        v2f pvv; pvv.x = fmaf(sPs, 1.f/9.f, q3);   pvv.y = fmaf(bw2, sp2, q3);
        v2f ylv = sp(yb.yl);
        v2f u1v = ylv - m2v*hv;
        v2f vdav = sp(yb.ydy) - m2v*(sp(2.f*yb.yl) - m2v*hv);
        v2f denv = sp(1.f) + pvv*hv;
        v2f rv  = rsq2(denv);
        v2f puv = pvv*(rv*rv);
        v2f pu1 = puv*u1v;
        v2f quadv = vdav - pu1*u1v;
        v2f euv = m2v + pu1;

        // mixing (log2 domain; det^(-1/2) via rs/rv factors; q12e precomputed)
        float q11e = QK*quad11;
        float q21e = QK*quadv.x, q22e = QK*quadv.y;
        float Mq = fmaxf(fmaxf(q11e, yb.q12e), fmaxf(q21e, q22e));
        float w11 = pp1*rs        * fexp2(q11e - Mq);
        float w12 = pf2*C12D      * fexp2(yb.q12e - Mq);
        float w21 = pp2*rv.x      * fexp2(q21e - Mq);
        float w22 = pf2*P22F*rv.y * fexp2(q22e - Mq);
        float pr1n = w11 + w12, pr2n = w21 + w22;
        float ssum = pr1n + pr2n;
        acc2 += Mq + flog2(ssum);
        float inv1 = frcp(fmaf(EPSF, ssum, pr1n));
        float inv2 = frcp(fmaf(EPSF, ssum, pr2n));
        float issum = frcp(ssum);
        float W11 = w11*inv1, W12 = w12*inv1;
        float W21 = w21*inv2, W22 = w22*inv2;
        pf1 = fmaf(pr1n, issum, EPSF);
        pf2 = fmaf(pr2n, issum, EPSF);
        float W11i = W11 * iM;                  // folds Ci = SC/det into collapse

        // collapse regime 1 (symmetric P; branch-12 posterior = diag(pk))
        float ne0 = fmaf(W12, yb.f0, W11*eu0);
        float ne1 = fmaf(W12, yb.f1, W11*eu1);
        float ne2 = fmaf(W12, yb.f2, W11*eu2);
        float da0 = eu0-ne0, da1 = eu1-ne1, da2 = eu2-ne2;
        float db0 = yb.f0-ne0, db1 = yb.f1-ne1, db2 = yb.f2-ne2;
        p00 = fmaf(W12, fmaf(db0, db0, pk0), fmaf(W11, da0*da0, W11i*SC00));
        p01 = fmaf(W12, db0*db1,             fmaf(W11, da0*da1, W11i*SC01));
        p02 = fmaf(W12, db0*db2,             fmaf(W11, da0*da2, W11i*SC02));
        p11 = fmaf(W12, fmaf(db1, db1, pk1), fmaf(W11, da1*da1, W11i*SC11));
        p12 = fmaf(W12, db1*db2,             fmaf(W11, da1*da2, W11i*SC12));
        p22 = fmaf(W12, fmaf(db2, db2, pk2), fmaf(W11, da2*da2, W11i*SC22));
        se0 = ne0; se1 = ne1; se2 = ne2;

        // collapse regime 2
        float nm2 = fmaf(W22, euv.y, W21*euv.x);
        v2f dcv = euv - sp(nm2);
        v2f tv = puv + dcv*dcv;
        sp2 = fmaf(W22, tv.y, W21*tv.x);
        sm2 = nm2;
    };

    // pipeline: loads for buffer X land one full step before computeYB(X)
    Yr A, B; YB ya, yb;
    loadY(A, 0);
    loadY(B, 1);
    ya = computeYB(A);
    for (int t = 0; t < Nt; t += 2) {
        step(ya);
        yb = computeYB(B);                        // B loaded >= 1 step ago
        if (t + 2 < Nt) loadY(A, t + 2);
        step(yb);
        if (t + 2 < Nt) ya = computeYB(A);        // A covered by step(yb)
        if (t + 3 < Nt) loadY(B, t + 3);
    }

    // one result per lane; wave-reduce; one partial per block (1 wave/block)
    float acc = valid ? (acc2 + (float)Nt * CC) * LN2 : 0.f;
    #pragma unroll
    for (int off = 32; off; off >>= 1) acc += __shfl_down(acc, off, 64);
    if (lane == 0) partial[blockIdx.x] = acc;
}

__global__ __launch_bounds__(64)
void reduce_k(const float* __restrict__ part, float* __restrict__ out, int nb)
{
    float s = 0.f;
    for (int i = threadIdx.x; i < nb; i += 64) s += part[i];
    #pragma unroll
    for (int off = 32; off; off >>= 1) s += __shfl_down(s, off, 64);
    if (threadIdx.x == 0) out[0] = s;
}

extern "C" void kernel_launch(void* const* d_in, const int* in_sizes, int n_in,
                              void* d_out, int out_size, void* d_ws, size_t ws_size,
                              hipStream_t stream)
{
    const float* y    = (const float*)d_in[0];
    const float* pBG  = (const float*)d_in[1];
    const float* pBT  = (const float*)d_in[2];
    const float* pBB  = (const float*)d_in[3];
    const float* pBW  = (const float*)d_in[4];
    const float* lam1 = (const float*)d_in[5];
    const float* lam2 = (const float*)d_in[6];
    const float* qd   = (const float*)d_in[7];
    const float* rd   = (const float*)d_in[8];
    const float* pG1  = (const float*)d_in[9];
    const float* pG2  = (const float*)d_in[10];

    const int total = in_sizes[0];
    const int Nt = 64, O = 9;
    const int N = total / (Nt * O);
    const int blocks = (N + 63) / 64;            // 1 series per lane

    float* partial = (float*)d_ws;
    kf_kernel<<<blocks, 64, 0, stream>>>(y, pBG, pBT, pBB, pBW, lam1, lam2,
                                         qd, rd, pG1, pG2, partial, N, Nt);
    reduce_k<<<1, 64, 0, stream>>>(partial, (float*)d_out, blocks);
}